// Round 9
// baseline (351.835 us; speedup 1.0000x reference)
//
#include <hip/hip_runtime.h>
#include <math.h>

typedef unsigned long long u64;
typedef unsigned int u32;

#define NB 16
#define SL 1024
#define DIM 16
#define MDIM 16
#define KNN 8
#define EH 66    /* edge hidden */
#define CH 64    /* coors hidden */
#define NHID 32  /* node hidden */
#define LN_EPS 1e-5f
#define W1T_STRIDE 36
#define ABSTRIDE 72   /* A/B table: per node 2 halves of 36 (33 used) */

__device__ __forceinline__ float silu_f(float x) {
    return x / (1.0f + __expf(-x));
}

// ---------------- init ----------------
__global__ __launch_bounds__(256) void init_kernel(
    const float* __restrict__ coords, const int* __restrict__ residues,
    const float* __restrict__ token_emb, const float* __restrict__ pos_emb,
    float* __restrict__ coordsA, float* __restrict__ featsA)
{
    const int nid = blockIdx.x * 256 + threadIdx.x;
    if (nid >= NB * SL) return;
    const int l = nid & (SL - 1);
    const int r = residues[nid];
#pragma unroll
    for (int c = 0; c < DIM; ++c)
        featsA[nid * DIM + c] = token_emb[r * DIM + c] + pos_emb[l * DIM + c];
#pragma unroll
    for (int c = 0; c < 3; ++c)
        coordsA[nid * 3 + c] = coords[nid * 3 + c];
}

// ---------------- weight transpose/pack ----------------
__global__ __launch_bounds__(256) void pack_kernel(
    const float* __restrict__ ew1, const float* __restrict__ cw1,
    const float* __restrict__ nw1, const float* __restrict__ nw2,
    float* __restrict__ w1t, float* __restrict__ cw1t,
    float* __restrict__ nw1t, float* __restrict__ nw2t)
{
    const int stride = gridDim.x * 256;
    const int t0 = blockIdx.x * 256 + threadIdx.x;
    for (int idx = t0; idx < 3 * EH * 33; idx += stride) {
        int d = idx / (EH * 33); int r = idx - d * EH * 33; int u = r / 33; int c = r - u * 33;
        w1t[(d * EH + u) * W1T_STRIDE + c] = ew1[(d * 33 + c) * EH + u];
    }
    for (int idx = t0; idx < 3 * CH * 16; idx += stride) {
        int d = idx / (CH * 16); int r = idx - d * CH * 16; int t = r >> 4; int v = r & 15;
        cw1t[(d * CH + t) * 16 + v] = cw1[(d * 16 + v) * CH + t];
    }
    for (int idx = t0; idx < 3 * NHID * 32; idx += stride) {
        int d = idx / (NHID * 32); int r = idx - d * NHID * 32; int u = r >> 5; int c = r & 31;
        nw1t[(d * NHID + u) * 32 + c] = nw1[(d * 32 + c) * NHID + u];
    }
    for (int idx = t0; idx < 3 * 16 * 32; idx += stride) {
        int d = idx / (16 * 32); int r = idx - d * 16 * 32; int c = r >> 5; int u = r & 31;
        nw2t[(d * 16 + c) * 32 + u] = nw2[(d * 32 + u) * 16 + c];
    }
}

// ---------------- per-node edge-MLP1 precompute for layer 0 ----------------
__global__ __launch_bounds__(256) void nodepre_kernel(
    const int d, const float* __restrict__ featsIn,
    const float* __restrict__ w1t, const float* __restrict__ g_eb1,
    float* __restrict__ Atab, float* __restrict__ Btab)
{
    __shared__ float s_w1[EH * W1T_STRIDE];
    const int tid = threadIdx.x;
    for (int t = tid; t < EH * W1T_STRIDE; t += 256) s_w1[t] = w1t[d * EH * W1T_STRIDE + t];
    __syncthreads();

    const int t0 = blockIdx.x * 256 + tid;   // 0..32767
    const int n = t0 >> 1;
    const int h = t0 & 1;
    float f[16];
    {
        const float4* pp = (const float4*)(featsIn + (size_t)n * DIM);
        float4 a = pp[0], c2 = pp[1], c3 = pp[2], c4 = pp[3];
        f[0]=a.x; f[1]=a.y; f[2]=a.z; f[3]=a.w;
        f[4]=c2.x; f[5]=c2.y; f[6]=c2.z; f[7]=c2.w;
        f[8]=c3.x; f[9]=c3.y; f[10]=c3.z; f[11]=c3.w;
        f[12]=c4.x; f[13]=c4.y; f[14]=c4.z; f[15]=c4.w;
    }
    const int ub = h * 33;
    float* Ao = Atab + (size_t)n * ABSTRIDE + 36 * h;
    float* Bo = Btab + (size_t)n * ABSTRIDE + 36 * h;
#pragma unroll 3
    for (int t = 0; t < 33; ++t) {
        const float* wr = &s_w1[(ub + t) * W1T_STRIDE];
        float a0 = g_eb1[d * EH + ub + t], a1 = 0.f, b0 = 0.f, b1 = 0.f;
#pragma unroll
        for (int c = 0; c < 16; c += 2) {
            a0 = fmaf(f[c],     wr[c],          a0);
            a1 = fmaf(f[c + 1], wr[c + 1],      a1);
            b0 = fmaf(f[c],     wr[16 + c],     b0);
            b1 = fmaf(f[c + 1], wr[16 + c + 1], b1);
        }
        Ao[t] = a0 + a1;
        Bo[t] = b0 + b1;
    }
}

// ---------------- kNN: wave handles 2 queries, candidates in LDS (one b128 feeds both) ----------------
#define CSU(x, y) { u32 mn = min(lst[x], lst[y]); u32 mx = max(lst[x], lst[y]); lst[x] = mn; lst[y] = mx; }

__device__ __forceinline__ void butterfly8(u32* lst) {
#pragma unroll
    for (int m = 1; m < 64; m <<= 1) {
        u32 o[8];
#pragma unroll
        for (int t = 0; t < 8; ++t) o[t] = (u32)__shfl_xor((int)lst[7 - t], m, 64);
#pragma unroll
        for (int t = 0; t < 8; ++t) lst[t] = min(lst[t], o[t]);
        CSU(0, 4) CSU(1, 5) CSU(2, 6) CSU(3, 7)
        CSU(0, 2) CSU(1, 3) CSU(4, 6) CSU(5, 7)
        CSU(0, 1) CSU(2, 3) CSU(4, 5) CSU(6, 7)
    }
}

__device__ __forceinline__ void ins8(u32* lst, u32 key) {
#pragma unroll
    for (int p = 7; p >= 1; --p)
        lst[p] = (key < lst[p]) ? ((key < lst[p - 1]) ? lst[p - 1] : key) : lst[p];
    lst[0] = min(key, lst[0]);
}

__device__ __forceinline__ u32 mk_key(int j, int i, int len, float dist) {
    const bool valid = j < len;
    const u32 kd = (__float_as_uint(dist) | 0x80000000u) & 0xFFFFFC00u;
    u32 key = valid ? kd : 0xC7C35000u;                           // key(1e5f)
    if (valid && (j == i + 1 || j + 1 == i)) key = 0x80000000u;   // key(0.0f) adjacency
    if (j == i) key = 0x407FFC00u;                                // key(-1.0f) self
    return key | (u32)j;
}

__global__ __launch_bounds__(1024, 8) void knn_kernel(
    const float* __restrict__ coords, const int* __restrict__ lengths,
    int* __restrict__ idxbuf)
{
    __shared__ float4 s_cand4[SL];        // 16 KB
    const int tid = threadIdx.x;
    const int b = blockIdx.x >> 5;
    const int i0 = (blockIdx.x & 31) << 5;   // 32 queries per block
    const int len = lengths[b];
    const float* cb = coords + (size_t)b * SL * 3;
    s_cand4[tid] = make_float4(cb[tid * 3 + 0], cb[tid * 3 + 1], cb[tid * 3 + 2], 0.0f);
    __syncthreads();

    const int wv = tid >> 6;
    const int lane = tid & 63;
    const int iA = i0 + 2 * wv;          // wave-uniform pair of queries
    const int iB = iA + 1;
    const float4 cA = s_cand4[iA];
    const float4 cB = s_cand4[iB];

    u32 lstA[8], lstB[8];
#pragma unroll
    for (int t = 0; t < 8; ++t) { lstA[t] = 0xFFFFFFFFu; lstB[t] = 0xFFFFFFFFu; }

#pragma unroll 4
    for (int t = 0; t < 16; ++t) {
        const int j = t * 64 + lane;
        const float4 cj = s_cand4[j];
        const float dxA = cA.x - cj.x, dyA = cA.y - cj.y, dzA = cA.z - cj.z;
        const float dxB = cB.x - cj.x, dyB = cB.y - cj.y, dzB = cB.z - cj.z;
        const float dA = dxA * dxA + dyA * dyA + dzA * dzA;
        const float dB = dxB * dxB + dyB * dyB + dzB * dzB;
        ins8(lstA, mk_key(j, iA, len, dA));
        ins8(lstB, mk_key(j, iB, len, dB));
    }

    butterfly8(lstA);
    butterfly8(lstB);

    if (lane < 2) {
        const u32* l = lane ? lstB : lstA;
        const size_t node = (size_t)b * SL + (lane ? iB : iA);
        int4 r0 = make_int4((int)(l[0] & 1023u), (int)(l[1] & 1023u), (int)(l[2] & 1023u), (int)(l[3] & 1023u));
        int4 r1 = make_int4((int)(l[4] & 1023u), (int)(l[5] & 1023u), (int)(l[6] & 1023u), (int)(l[7] & 1023u));
        ((int4*)idxbuf)[node * 2 + 0] = r0;
        ((int4*)idxbuf)[node * 2 + 1] = r1;
    }
}

// ---------------- EGNN layer: thread=edge, 2-way wave split; weights via wave-uniform
// global pointers (s_load path, zero DS-pipe cost); fused next-layer A/B or final ----------------
__global__ __launch_bounds__(256, 5) void layer_kernel(
    const int d,
    const float* __restrict__ coordsIn, float* __restrict__ coordsOut,
    const float* __restrict__ featsIn, float* __restrict__ featsOut,
    const int* __restrict__ idxbuf, const int* __restrict__ lengths,
    const float* __restrict__ Ain, const float* __restrict__ Bin,
    float* __restrict__ Aout, float* __restrict__ Bout,
    const float* __restrict__ w1t, const float* __restrict__ g_eb1,
    const float* __restrict__ g_ew2, const float* __restrict__ g_eb2,
    const float* __restrict__ cw1t, const float* __restrict__ g_cb1,
    const float* __restrict__ g_cw2, const float* __restrict__ g_cb2,
    const float* __restrict__ g_lng, const float* __restrict__ g_lnb,
    const float* __restrict__ nw1t, const float* __restrict__ g_nb1,
    const float* __restrict__ nw2t, const float* __restrict__ g_nb2,
    const float* __restrict__ fw, const float* __restrict__ fb,
    float* __restrict__ out)
{
    __shared__ float s_buf[2][16][66];    // edge-MLP partial exchange
    __shared__ float s_wx[2][2][64];      // coors partials
    __shared__ float s_nw1[NHID * 36];    // per-lane-row tables stay in LDS
    __shared__ float s_nw2[16 * 36];
    __shared__ float s_w1n[EH * 36];      // next layer W1 (epilogue), d<2 only

    const int tid = threadIdx.x;
    for (int t = tid; t < NHID * 32; t += 256) s_nw1[(t >> 5) * 36 + (t & 31)] = nw1t[d * NHID * 32 + t];
    for (int t = tid; t < 16 * 32; t += 256) s_nw2[(t >> 5) * 36 + (t & 31)] = nw2t[d * 16 * 32 + t];
    if (d < 2) {
        for (int t = tid; t < EH * 36; t += 256) s_w1n[t] = w1t[(d + 1) * EH * 36 + t];
    }

    const int wv = tid >> 6;
    const int g = wv >> 1;           // edge group (64 edges)
    const int h = wv & 1;            // half (wave-uniform)
    const int lane = tid & 63;
    const int e = blockIdx.x * 128 + g * 64 + lane;
    const int n = e >> 3;
    const int b = n >> 10;
    const int i = n & (SL - 1);
    const int k = lane & 7;
    const int len = lengths[b];
    const int j = idxbuf[e];
    const bool em = (i < len) && (j < len);

    // coords / rel / rd
    float ci[3], rel[3];
    {
        const float* cp = coordsIn + (size_t)n * 3;
        const float* cq = coordsIn + ((size_t)b * SL + j) * 3;
        ci[0] = cp[0]; ci[1] = cp[1]; ci[2] = cp[2];
        rel[0] = ci[0] - cq[0]; rel[1] = ci[1] - cq[1]; rel[2] = ci[2] - cq[2];
    }
    const float rd = fmaf(rel[0], rel[0], fmaf(rel[1], rel[1], rel[2] * rel[2]));

    // fi only needed by h==1
    float fi[16];
    if (h) {
        const float4* pp = (const float4*)(featsIn + (size_t)n * DIM);
        float4 a = pp[0], c2 = pp[1], c3 = pp[2], c4 = pp[3];
        fi[0]=a.x; fi[1]=a.y; fi[2]=a.z; fi[3]=a.w;
        fi[4]=c2.x; fi[5]=c2.y; fi[6]=c2.z; fi[7]=c2.w;
        fi[8]=c3.x; fi[9]=c3.y; fi[10]=c3.z; fi[11]=c3.w;
        fi[12]=c4.x; fi[13]=c4.y; fi[14]=c4.z; fi[15]=c4.w;
    }

    const float4* Aq = (const float4*)(Ain + (size_t)n * ABSTRIDE + 36 * h);
    const float4* Bq = (const float4*)(Bin + ((size_t)b * SL + j) * ABSTRIDE + 36 * h);

    // ---- edge MLP half: units [h*33, h*33+33); weights wave-uniform -> s_load ----
    const int ub = h * 33;
    const float* w1base = w1t + ((size_t)d * EH + ub) * W1T_STRIDE;   // col 32 = rd weight
    const float* w2base = g_ew2 + ((size_t)d * EH + ub) * 16;
    const float* eb2r = g_eb2 + d * 16;
    float macc[16];
#pragma unroll
    for (int v = 0; v < 16; ++v) macc[v] = h ? 0.0f : eb2r[v];
#pragma unroll
    for (int c = 0; c < 9; ++c) {
        const float4 a4 = Aq[c];
        const float4 b4 = Bq[c];
        const float av[4] = {a4.x, a4.y, a4.z, a4.w};
        const float bv[4] = {b4.x, b4.y, b4.z, b4.w};
#pragma unroll
        for (int q = 0; q < 4; ++q) {
            const int t = 4 * c + q;
            if (t < 33) {
                const float hin = fmaf(rd, w1base[t * W1T_STRIDE + 32], av[q] + bv[q]);
                const float hh = silu_f(hin);
                const float* w2r = w2base + t * 16;
#pragma unroll
                for (int v = 0; v < 16; ++v) macc[v] = fmaf(hh, w2r[v], macc[v]);
            }
        }
    }

    // ---- combine halves via LDS (also guarantees staging visibility) ----
    if (h) {
#pragma unroll
        for (int v = 0; v < 16; ++v) s_buf[g][v][lane] = macc[v];
    }
    __syncthreads();   // sync1
    float mm[16];
    if (!h) {
#pragma unroll
        for (int v = 0; v < 16; ++v) { macc[v] += s_buf[g][v][lane]; mm[v] = silu_f(macc[v]); s_buf[g][v][lane] = mm[v]; }
    }
    __syncthreads();   // sync2
    if (h) {
#pragma unroll
        for (int v = 0; v < 16; ++v) mm[v] = s_buf[g][v][lane];
    }

    // ---- coors MLP half: rows [h*32, h*32+32); weights uniform -> s_load ----
    {
        const int tb = h * 32;
        const float* c1base = cw1t + ((size_t)d * CH + tb) * 16;
        const float* cb1r = g_cb1 + d * CH + tb;
        const float* cw2r = g_cw2 + d * CH + tb;
        float wa = 0.f;
#pragma unroll 4
        for (int tt = 0; tt < 32; ++tt) {
            const float* cr = c1base + tt * 16;
            float a0 = cb1r[tt], a1 = 0.f;
#pragma unroll
            for (int v = 0; v < 16; v += 2) {
                a0 = fmaf(mm[v], cr[v], a0);
                a1 = fmaf(mm[v + 1], cr[v + 1], a1);
            }
            wa = fmaf(silu_f(a0 + a1), cw2r[tt], wa);
        }
        s_wx[g][h][lane] = wa;
    }
    __syncthreads();   // sync3

    if (!h) {
        // ---- coordinate update ----
        const float we = em ? (s_wx[g][0][lane] + s_wx[g][1][lane] + g_cb2[d]) : 0.f;
        float wr0 = we * rel[0], wr1 = we * rel[1], wr2 = we * rel[2];
#pragma unroll
        for (int s = 1; s < 8; s <<= 1) {
            wr0 += __shfl_xor(wr0, s, 64);
            wr1 += __shfl_xor(wr1, s, 64);
            wr2 += __shfl_xor(wr2, s, 64);
        }
        if (k == 0) {
            coordsOut[(size_t)n * 3 + 0] = ci[0] + wr0;
            coordsOut[(size_t)n * 3 + 1] = ci[1] + wr1;
            coordsOut[(size_t)n * 3 + 2] = ci[2] + wr2;
        }
    } else {
        // ---- m_i (masked sum over octet) ----
        float mi_[16];
#pragma unroll
        for (int v = 0; v < 16; ++v) mi_[v] = em ? mm[v] : 0.f;
#pragma unroll
        for (int s = 1; s < 8; s <<= 1) {
#pragma unroll
            for (int v = 0; v < 16; ++v) mi_[v] += __shfl_xor(mi_[v], s, 64);
        }
        // ---- LayerNorm(fi) ----
        float mu = 0.f;
#pragma unroll
        for (int c = 0; c < 16; ++c) mu += fi[c];
        mu *= 0.0625f;
        float var = 0.f;
#pragma unroll
        for (int c = 0; c < 16; ++c) { const float dd = fi[c] - mu; var = fmaf(dd, dd, var); }
        var *= 0.0625f;
        const float rs = rsqrtf(var + LN_EPS);
        float nn[16];
#pragma unroll
        for (int c = 0; c < 16; ++c) nn[c] = fmaf((fi[c] - mu) * rs, g_lng[d * 16 + c], g_lnb[d * 16 + c]);

        // node MLP hidden: lane k owns units 4k..4k+3 (rows in LDS; broadcast across octets)
        float nh[4];
#pragma unroll
        for (int qq = 0; qq < 4; ++qq) {
            const int u = k * 4 + qq;
            const float* nr = &s_nw1[u * 36];
            float a0 = g_nb1[d * 32 + u], a1 = 0.f;
#pragma unroll
            for (int c = 0; c < 16; c += 2) {
                a0 = fmaf(nn[c], nr[c], a0);
                a1 = fmaf(nn[c + 1], nr[c + 1], a1);
            }
#pragma unroll
            for (int v = 0; v < 16; v += 2) {
                a0 = fmaf(mi_[v], nr[16 + v], a0);
                a1 = fmaf(mi_[v + 1], nr[16 + v + 1], a1);
            }
            nh[qq] = silu_f(a0 + a1);
        }
        // node MLP out: lane k -> channels 2k, 2k+1 via shfl gather over octet
        const int c0 = 2 * k, c1 = 2 * k + 1;
        const float* w2a = &s_nw2[c0 * 36];
        const float* w2b = &s_nw2[c1 * 36];
        float o0 = g_nb2[d * 16 + c0], o1 = g_nb2[d * 16 + c1];
        const int lbase = lane & ~7;
#pragma unroll
        for (int u = 0; u < 32; ++u) {
            const float v = __shfl(nh[u & 3], lbase + (u >> 2), 64);
            o0 = fmaf(v, w2a[u], o0);
            o1 = fmaf(v, w2b[u], o1);
        }
        const float nf0 = fi[c0] + o0;
        const float nf1 = fi[c1] + o1;

        if (d == 2) {
            // ---- fused final projection: delta = feats @ fw + fb ----
            float p0 = nf0 * fw[c0 * 3 + 0] + nf1 * fw[c1 * 3 + 0];
            float p1 = nf0 * fw[c0 * 3 + 1] + nf1 * fw[c1 * 3 + 1];
            float p2 = nf0 * fw[c0 * 3 + 2] + nf1 * fw[c1 * 3 + 2];
#pragma unroll
            for (int s = 1; s < 8; s <<= 1) {
                p0 += __shfl_xor(p0, s, 64);
                p1 += __shfl_xor(p1, s, 64);
                p2 += __shfl_xor(p2, s, 64);
            }
            if (k == 0) {
                out[(size_t)n * 3 + 0] = p0 + fb[0];
                out[(size_t)n * 3 + 1] = p1 + fb[1];
                out[(size_t)n * 3 + 2] = p2 + fb[2];
            }
        } else {
            ((float2*)featsOut)[(size_t)n * 8 + k] = make_float2(nf0, nf1);
            // ---- fused next-layer A/B: gather full new feats via octet shfl ----
            float f[16];
#pragma unroll
            for (int m = 0; m < 8; ++m) {
                f[2 * m]     = __shfl(nf0, lbase + m, 64);
                f[2 * m + 1] = __shfl(nf1, lbase + m, 64);
            }
#pragma unroll
            for (int m = 0; m < 9; ++m) {
                const int u = k + 8 * m;
                if (u < EH) {
                    const float* row = &s_w1n[u * 36];
                    float a0 = g_eb1[(d + 1) * EH + u], a1 = 0.f, b0 = 0.f, b1 = 0.f;
#pragma unroll
                    for (int c = 0; c < 16; c += 2) {
                        a0 = fmaf(f[c],     row[c],          a0);
                        a1 = fmaf(f[c + 1], row[c + 1],      a1);
                        b0 = fmaf(f[c],     row[16 + c],     b0);
                        b1 = fmaf(f[c + 1], row[16 + c + 1], b1);
                    }
                    const int half = (u >= 33) ? 1 : 0;
                    const size_t off = (size_t)n * ABSTRIDE + 36 * half + (u - 33 * half);
                    Aout[off] = a0 + a1;
                    Bout[off] = b0 + b1;
                }
            }
        }
    }
}

extern "C" void kernel_launch(void* const* d_in, const int* in_sizes, int n_in,
                              void* d_out, int out_size, void* d_ws, size_t ws_size,
                              hipStream_t stream) {
    const float* coords    = (const float*)d_in[0];
    const int*   residues  = (const int*)d_in[1];
    const int*   lengths   = (const int*)d_in[2];
    const float* token_emb = (const float*)d_in[3];
    const float* pos_emb   = (const float*)d_in[4];
    const float* ew1 = (const float*)d_in[5];
    const float* eb1 = (const float*)d_in[6];
    const float* ew2 = (const float*)d_in[7];
    const float* eb2 = (const float*)d_in[8];
    const float* cw1 = (const float*)d_in[9];
    const float* cb1 = (const float*)d_in[10];
    const float* cw2 = (const float*)d_in[11];
    const float* cb2 = (const float*)d_in[12];
    const float* lng = (const float*)d_in[13];
    const float* lnb = (const float*)d_in[14];
    const float* nw1 = (const float*)d_in[15];
    const float* nb1 = (const float*)d_in[16];
    const float* nw2 = (const float*)d_in[17];
    const float* nb2 = (const float*)d_in[18];
    const float* fw  = (const float*)d_in[19];
    const float* fb  = (const float*)d_in[20];

    float* ws = (float*)d_ws;
    float* coordsA = ws;                               // 49152
    float* coordsB = coordsA + NB * SL * 3;            // 49152
    float* featsA  = coordsB + NB * SL * 3;            // 262144
    float* featsB  = featsA + NB * SL * DIM;           // 262144
    int*   idxbuf  = (int*)(featsB + NB * SL * DIM);   // 131072 ints
    float* w1t  = (float*)(idxbuf + NB * SL * KNN);    // 7128
    float* cw1t = w1t + 3 * EH * W1T_STRIDE;           // 3072
    float* nw1t = cw1t + 3 * CH * 16;                  // 3072
    float* nw2t = nw1t + 3 * NHID * 32;                // 1536
    float* Atab0 = nw2t + 3 * 16 * 32;                 // 1179648 each
    float* Btab0 = Atab0 + (size_t)NB * SL * ABSTRIDE;
    float* Atab1 = Btab0 + (size_t)NB * SL * ABSTRIDE;
    float* Btab1 = Atab1 + (size_t)NB * SL * ABSTRIDE;

    pack_kernel<<<32, 256, 0, stream>>>(ew1, cw1, nw1, nw2, w1t, cw1t, nw1t, nw2t);
    init_kernel<<<NB * SL / 256, 256, 0, stream>>>(coords, residues, token_emb, pos_emb, coordsA, featsA);
    nodepre_kernel<<<NB * SL * 2 / 256, 256, 0, stream>>>(0, featsA, w1t, eb1, Atab0, Btab0);

    float* cIn = coordsA; float* cOut = coordsB;
    float* fIn = featsA;  float* fOut = featsB;
    float* Ain = Atab0; float* Bin = Btab0;
    float* Aout = Atab1; float* Bout = Btab1;
    for (int d = 0; d < 3; ++d) {
        knn_kernel<<<NB * 32, 1024, 0, stream>>>(cIn, lengths, idxbuf);
        layer_kernel<<<NB * SL * KNN / 128, 256, 0, stream>>>(d, cIn, cOut, fIn, fOut, idxbuf, lengths,
            Ain, Bin, Aout, Bout, w1t, eb1, ew2, eb2, cw1t, cb1, cw2, cb2,
            lng, lnb, nw1t, nb1, nw2t, nb2, fw, fb, (float*)d_out);
        float* t;
        t = cIn; cIn = cOut; cOut = t;
        t = fIn; fIn = fOut; fOut = t;
        t = Ain; Ain = Aout; Aout = t;
        t = Bin; Bin = Bout; Bout = t;
    }
}